// Round 3
// baseline (658.049 us; speedup 1.0000x reference)
//
#include <hip/hip_runtime.h>
#include <hip/hip_bf16.h>

// B=2, S=2048, D_MODEL=1024, H=16, D_HEAD=64.
// Inputs/outputs are FP32 on device (reference is jnp.float32); mask is int32
// (nonzero = masked, add -9e10). Internal compute: bf16 MFMA w/ fp32 accum.

typedef __bf16 bf16x8 __attribute__((ext_vector_type(8)));
typedef float f32x4 __attribute__((ext_vector_type(4)));

#define S_LEN 2048
#define DM 1024
#define NH 16
#define DH 64
#define MROWS 4096  // B*S

static __device__ __forceinline__ unsigned short f2bf(float f) {
    __hip_bfloat16 h = __float2bfloat16(f);
    unsigned short u; __builtin_memcpy(&u, &h, 2); return u;
}

static __device__ __forceinline__ bf16x8 cvt8(float4 a, float4 b) {
    bf16x8 o;
    o[0] = (__bf16)a.x; o[1] = (__bf16)a.y; o[2] = (__bf16)a.z; o[3] = (__bf16)a.w;
    o[4] = (__bf16)b.x; o[5] = (__bf16)b.y; o[6] = (__bf16)b.z; o[7] = (__bf16)b.w;
    return o;
}

// Y = X @ W^T + bias.  X: (4096 x 1024). W: (1024 x 1024) fp32. Internals bf16.
// mode 0/1: dstb[(b*16+h)*S + s][dh] head-split bf16 (q_ws / k_ws)
// mode 2:   dstb[(b*16+h)*64 + dh][s] transposed bf16 (vt_ws)
// mode 3:   X is bf16 (ctx_ws), dstf[row][col] fp32 row-major (d_out)
__global__ __launch_bounds__(256)
void gemm_bt(const float* __restrict__ Xf, const unsigned short* __restrict__ Xb,
             const float* __restrict__ W,
             const float* __restrict__ bias,
             unsigned short* __restrict__ dstb, float* __restrict__ dstf, int mode)
{
    __shared__ __align__(16) unsigned short As[128 * 40];  // +8 pad per row
    __shared__ __align__(16) unsigned short Bs[128 * 40];
    const int tid  = threadIdx.x;
    const int m0   = blockIdx.y * 128;
    const int n0   = blockIdx.x * 128;
    const int lane = tid & 63;
    const int w    = tid >> 6;
    const int wm   = (w >> 1) * 64, wn = (w & 1) * 64;
    const int lr   = lane & 15;   // frag row / C col
    const int lg   = lane >> 4;   // k-chunk group / C row group

    f32x4 acc[4][4];
#pragma unroll
    for (int i = 0; i < 4; i++)
#pragma unroll
        for (int j = 0; j < 4; j++) acc[i][j] = f32x4{0.f, 0.f, 0.f, 0.f};

    for (int k0 = 0; k0 < DM; k0 += 32) {
        __syncthreads();
#pragma unroll
        for (int i = 0; i < 2; i++) {
            int idx = tid + i * 256;
            int r = idx >> 2, c = (idx & 3) * 8;
            size_t gx = (size_t)(m0 + r) * DM + k0 + c;
            if (mode == 3) {
                *(bf16x8*)(&As[r * 40 + c]) = *(const bf16x8*)(&Xb[gx]);
            } else {
                float4 a0 = *(const float4*)(&Xf[gx]);
                float4 a1 = *(const float4*)(&Xf[gx + 4]);
                *(bf16x8*)(&As[r * 40 + c]) = cvt8(a0, a1);
            }
            size_t gw = (size_t)(n0 + r) * DM + k0 + c;
            float4 b0 = *(const float4*)(&W[gw]);
            float4 b1 = *(const float4*)(&W[gw + 4]);
            *(bf16x8*)(&Bs[r * 40 + c]) = cvt8(b0, b1);
        }
        __syncthreads();
        bf16x8 af[4], bfr[4];
#pragma unroll
        for (int mi = 0; mi < 4; mi++)
            af[mi] = *(const bf16x8*)(&As[(wm + mi * 16 + lr) * 40 + lg * 8]);
#pragma unroll
        for (int ni = 0; ni < 4; ni++)
            bfr[ni] = *(const bf16x8*)(&Bs[(wn + ni * 16 + lr) * 40 + lg * 8]);
#pragma unroll
        for (int mi = 0; mi < 4; mi++)
#pragma unroll
            for (int ni = 0; ni < 4; ni++)
                acc[mi][ni] = __builtin_amdgcn_mfma_f32_16x16x32_bf16(
                    af[mi], bfr[ni], acc[mi][ni], 0, 0, 0);
    }

    // Epilogue. C/D layout: col = lane&15, row = (lane>>4)*4 + reg.
#pragma unroll
    for (int mi = 0; mi < 4; mi++) {
#pragma unroll
        for (int ni = 0; ni < 4; ni++) {
            const int gcol = n0 + wn + ni * 16 + lr;
            const float bv = bias[gcol];
            const int grow0 = m0 + wm + mi * 16 + lg * 4;
            if (mode == 2) {
                int b = grow0 >> 11, s = grow0 & (S_LEN - 1);
                int h = gcol >> 6, dh = gcol & 63;
                unsigned short us[4];
#pragma unroll
                for (int r = 0; r < 4; r++) us[r] = f2bf(acc[mi][ni][r] + bv);
                size_t di = ((size_t)(b * NH + h) * DH + dh) * S_LEN + s;
                *(ushort2*)(&dstb[di])     = ushort2{us[0], us[1]};
                *(ushort2*)(&dstb[di + 2]) = ushort2{us[2], us[3]};
            } else {
#pragma unroll
                for (int r = 0; r < 4; r++) {
                    int grow = grow0 + r;
                    float v = acc[mi][ni][r] + bv;
                    if (mode == 3) {
                        dstf[(size_t)grow * DM + gcol] = v;
                    } else {
                        int b = grow >> 11, s = grow & (S_LEN - 1);
                        int h = gcol >> 6, dh = gcol & 63;
                        dstb[((size_t)(b * NH + h) * S_LEN + s) * DH + dh] = f2bf(v);
                    }
                }
            }
        }
    }
}

// Flash attention: grid (S/64, B*H), 256 threads = 4 waves, 16 q-rows/wave.
__global__ __launch_bounds__(256)
void attn(const unsigned short* __restrict__ q_ws,
          const unsigned short* __restrict__ k_ws,
          const unsigned short* __restrict__ vt_ws,
          const int* __restrict__ mask,
          unsigned short* __restrict__ ctx_ws)
{
    __shared__ __align__(16) unsigned short P_lds[4][16 * 72];  // per-wave P tile
    const int tid = threadIdx.x, lane = tid & 63, w = tid >> 6;
    const int lr = lane & 15, lg = lane >> 4;
    const int bh = blockIdx.y;       // b*16 + h
    const int b  = bh >> 4;
    const int h  = bh & 15;
    const int q0 = blockIdx.x * 64 + w * 16;

    const unsigned short* qh = q_ws + (size_t)bh * S_LEN * DH;
    const unsigned short* kh = k_ws + (size_t)bh * S_LEN * DH;
    const unsigned short* vh = vt_ws + (size_t)bh * DH * S_LEN;
    const int* mrow = mask + (size_t)b * S_LEN * S_LEN;

    // Q A-fragments (A[m=lane&15][k=(lane>>4)*8+j]), kept in regs all loop.
    bf16x8 aq[2];
#pragma unroll
    for (int c = 0; c < 2; c++)
        aq[c] = *(const bf16x8*)(&qh[(size_t)(q0 + lr) * DH + c * 32 + lg * 8]);

    f32x4 acc[4];
#pragma unroll
    for (int di = 0; di < 4; di++) acc[di] = f32x4{0.f, 0.f, 0.f, 0.f};
    float mrun[4], lrun[4];
#pragma unroll
    for (int r = 0; r < 4; r++) { mrun[r] = -1e30f; lrun[r] = 0.f; }

    for (int kv0 = 0; kv0 < S_LEN; kv0 += 64) {
        f32x4 sf[4];
#pragma unroll
        for (int ni = 0; ni < 4; ni++) {
            const unsigned short* kr = &kh[(size_t)(kv0 + ni * 16 + lr) * DH + lg * 8];
            bf16x8 bk0 = *(const bf16x8*)(kr);
            bf16x8 bk1 = *(const bf16x8*)(kr + 32);
            f32x4 t = __builtin_amdgcn_mfma_f32_16x16x32_bf16(aq[0], bk0, f32x4{0.f,0.f,0.f,0.f}, 0,0,0);
            t = __builtin_amdgcn_mfma_f32_16x16x32_bf16(aq[1], bk1, t, 0,0,0);
            sf[ni] = t;
        }
#pragma unroll
        for (int ni = 0; ni < 4; ni++)
#pragma unroll
            for (int r = 0; r < 4; r++) {
                int qrow = q0 + lg * 4 + r;
                int mv = mrow[(size_t)qrow * S_LEN + kv0 + ni * 16 + lr];
                sf[ni][r] = sf[ni][r] * 0.125f + (mv != 0 ? -9e10f : 0.0f);
            }
        float mnew[4], alpha[4];
#pragma unroll
        for (int r = 0; r < 4; r++) {
            float v = fmaxf(fmaxf(sf[0][r], sf[1][r]), fmaxf(sf[2][r], sf[3][r]));
            v = fmaxf(v, __shfl_xor(v, 1));
            v = fmaxf(v, __shfl_xor(v, 2));
            v = fmaxf(v, __shfl_xor(v, 4));
            v = fmaxf(v, __shfl_xor(v, 8));
            mnew[r] = fmaxf(mrun[r], v);
            alpha[r] = __expf(fminf(mrun[r] - mnew[r], 0.f));
            mrun[r] = mnew[r];
        }
        float rs[4] = {0.f, 0.f, 0.f, 0.f};
#pragma unroll
        for (int ni = 0; ni < 4; ni++)
#pragma unroll
            for (int r = 0; r < 4; r++) {
                float p = __expf(fminf(sf[ni][r] - mnew[r], 0.f));
                sf[ni][r] = p;
                rs[r] += p;
            }
#pragma unroll
        for (int r = 0; r < 4; r++) {
            float v = rs[r];
            v += __shfl_xor(v, 1);
            v += __shfl_xor(v, 2);
            v += __shfl_xor(v, 4);
            v += __shfl_xor(v, 8);
            lrun[r] = alpha[r] * lrun[r] + v;
        }
#pragma unroll
        for (int di = 0; di < 4; di++)
#pragma unroll
            for (int r = 0; r < 4; r++) acc[di][r] *= alpha[r];

        // P (C-layout) -> LDS -> A-layout fragments. Per-wave region.
        unsigned short* pl = &P_lds[w][0];
#pragma unroll
        for (int ni = 0; ni < 4; ni++)
#pragma unroll
            for (int r = 0; r < 4; r++)
                pl[(lg * 4 + r) * 72 + ni * 16 + lr] = f2bf(sf[ni][r]);

        bf16x8 ap0 = *(const bf16x8*)(&pl[lr * 72 + lg * 8]);
        bf16x8 ap1 = *(const bf16x8*)(&pl[lr * 72 + 32 + lg * 8]);
#pragma unroll
        for (int di = 0; di < 4; di++) {
            const unsigned short* vr = &vh[(size_t)(di * 16 + lr) * S_LEN + kv0 + lg * 8];
            bf16x8 bv0 = *(const bf16x8*)(vr);
            bf16x8 bv1 = *(const bf16x8*)(vr + 32);
            acc[di] = __builtin_amdgcn_mfma_f32_16x16x32_bf16(ap0, bv0, acc[di], 0, 0, 0);
            acc[di] = __builtin_amdgcn_mfma_f32_16x16x32_bf16(ap1, bv1, acc[di], 0, 0, 0);
        }
    }

#pragma unroll
    for (int di = 0; di < 4; di++)
#pragma unroll
        for (int r = 0; r < 4; r++) {
            int qrow = q0 + lg * 4 + r;
            int col = h * DH + di * 16 + lr;
            float inv = 1.0f / fmaxf(lrun[r], 1e-37f);
            float v = acc[di][r] * inv;
            ctx_ws[((size_t)(b * S_LEN + qrow)) * DM + col] = f2bf(v);
        }
}

extern "C" void kernel_launch(void* const* d_in, const int* in_sizes, int n_in,
                              void* d_out, int out_size, void* d_ws, size_t ws_size,
                              hipStream_t stream)
{
    (void)in_sizes; (void)n_in; (void)out_size; (void)ws_size;
    const float* Q  = (const float*)d_in[0];
    const float* K  = (const float*)d_in[1];
    const float* V  = (const float*)d_in[2];
    const int*   Mk = (const int*)d_in[3];
    const float* Wq = (const float*)d_in[4];
    const float* bq = (const float*)d_in[5];
    const float* Wk = (const float*)d_in[6];
    const float* bk = (const float*)d_in[7];
    const float* Wv = (const float*)d_in[8];
    const float* bv = (const float*)d_in[9];
    const float* Wo = (const float*)d_in[10];
    const float* bo = (const float*)d_in[11];

    unsigned short* q_ws   = (unsigned short*)d_ws;
    unsigned short* k_ws   = q_ws  + (size_t)MROWS * DM;
    unsigned short* vt_ws  = k_ws  + (size_t)MROWS * DM;
    unsigned short* ctx_ws = vt_ws + (size_t)MROWS * DM;
    float* out = (float*)d_out;

    dim3 blk(256);
    gemm_bt<<<dim3(8, 32), blk, 0, stream>>>(Q, nullptr, Wq, bq, q_ws, nullptr, 0);
    gemm_bt<<<dim3(8, 32), blk, 0, stream>>>(K, nullptr, Wk, bk, k_ws, nullptr, 1);
    gemm_bt<<<dim3(8, 32), blk, 0, stream>>>(V, nullptr, Wv, bv, vt_ws, nullptr, 2);
    attn<<<dim3(32, 32), blk, 0, stream>>>(q_ws, k_ws, vt_ws, Mk, ctx_ws);
    gemm_bt<<<dim3(8, 32), blk, 0, stream>>>(nullptr, ctx_ws, Wo, bo, nullptr, out, 3);
}

// Round 4
// 507.866 us; speedup vs baseline: 1.2957x; 1.2957x over previous
//
#include <hip/hip_runtime.h>
#include <hip/hip_bf16.h>

// B=2, S=2048, D_MODEL=1024, H=16, D_HEAD=64.
// I/O fp32 (verified R3); mask int32 (nonzero = masked). Internals bf16 MFMA.

typedef __bf16 bf16x8 __attribute__((ext_vector_type(8)));
typedef float f32x4 __attribute__((ext_vector_type(4)));

#define S_LEN 2048
#define DM 1024
#define NH 16
#define DH 64
#define MROWS 4096  // B*S

static __device__ __forceinline__ unsigned short f2bf(float f) {
    __hip_bfloat16 h = __float2bfloat16(f);
    unsigned short u; __builtin_memcpy(&u, &h, 2); return u;
}

static __device__ __forceinline__ bf16x8 cvt8(float4 a, float4 b) {
    bf16x8 o;
    o[0] = (__bf16)a.x; o[1] = (__bf16)a.y; o[2] = (__bf16)a.z; o[3] = (__bf16)a.w;
    o[4] = (__bf16)b.x; o[5] = (__bf16)b.y; o[6] = (__bf16)b.z; o[7] = (__bf16)b.w;
    return o;
}

// fp32 -> bf16, two tensors per launch (blockIdx.y selects).
__global__ __launch_bounds__(256)
void cvt2(const float* __restrict__ sA, unsigned short* __restrict__ dA, int nA,
          const float* __restrict__ sB, unsigned short* __restrict__ dB, int nB)
{
    const float* s = blockIdx.y ? sB : sA;
    unsigned short* d = blockIdx.y ? dB : dA;
    int n = blockIdx.y ? nB : nA;
    int i = (blockIdx.x * 256 + threadIdx.x) * 8;
    if (i < n) {
        float4 a = *(const float4*)(s + i);
        float4 b = *(const float4*)(s + i + 4);
        *(bf16x8*)(d + i) = cvt8(a, b);
    }
}

// mask int32 [B*S][S] -> bit-packed [B*S][S/32] uint32 (bit kv&31 of word kv>>5)
__global__ __launch_bounds__(256)
void pack_mask(const int* __restrict__ m, unsigned* __restrict__ mb)
{
    const int lane = threadIdx.x & 63, w = threadIdx.x >> 6;
    const int row = blockIdx.x * 4 + w;          // 1024 blocks x 4 waves = 4096 rows
    const int* src = m + (size_t)row * S_LEN;
    unsigned* dst = mb + (size_t)row * (S_LEN / 32);
    for (int i = 0; i < 32; i++) {
        int v = src[i * 64 + lane];
        unsigned long long bm = __ballot(v != 0);
        if (lane == 0) { dst[i * 2] = (unsigned)bm; dst[i * 2 + 1] = (unsigned)(bm >> 32); }
    }
}

// Y = X @ W^T + bias. X bf16 (4096x1024), W bf16 (1024x1024). Tile 128Mx64N.
// mode 0/1: dstb[(b*16+h)*S + s][dh] head-split bf16 (q_ws/k_ws)
// mode 2:   dstb[(b*16+h)*64 + dh][s] transposed bf16 (vt_ws)
// mode 3:   dstf[row][col] fp32 row-major (d_out)
__global__ __launch_bounds__(256)
void gemm_bt(const unsigned short* __restrict__ X, const unsigned short* __restrict__ W,
             const float* __restrict__ bias,
             unsigned short* __restrict__ dstb, float* __restrict__ dstf, int mode)
{
    __shared__ __align__(16) unsigned short As[128 * 40];
    __shared__ __align__(16) unsigned short Bs[64 * 40];
    const int tid  = threadIdx.x;
    const int m0   = blockIdx.y * 128;
    const int n0   = blockIdx.x * 64;
    const int lane = tid & 63;
    const int w    = tid >> 6;
    const int wm   = (w >> 1) * 64, wn = (w & 1) * 32;
    const int lr   = lane & 15;
    const int lg   = lane >> 4;

    f32x4 acc[4][2];
#pragma unroll
    for (int i = 0; i < 4; i++)
#pragma unroll
        for (int j = 0; j < 2; j++) acc[i][j] = f32x4{0.f, 0.f, 0.f, 0.f};

    for (int k0 = 0; k0 < DM; k0 += 32) {
        __syncthreads();
        {
            int r = tid >> 2, c = (tid & 3) * 8;
            *(bf16x8*)(&As[r * 40 + c]) = *(const bf16x8*)(&X[(size_t)(m0 + r) * DM + k0 + c]);
            int r1 = (tid + 256) >> 2, c1 = ((tid + 256) & 3) * 8;
            *(bf16x8*)(&As[r1 * 40 + c1]) = *(const bf16x8*)(&X[(size_t)(m0 + r1) * DM + k0 + c1]);
            *(bf16x8*)(&Bs[r * 40 + c]) = *(const bf16x8*)(&W[(size_t)(n0 + r) * DM + k0 + c]);
        }
        __syncthreads();
        bf16x8 af[4], bfr[2];
#pragma unroll
        for (int mi = 0; mi < 4; mi++)
            af[mi] = *(const bf16x8*)(&As[(wm + mi * 16 + lr) * 40 + lg * 8]);
#pragma unroll
        for (int ni = 0; ni < 2; ni++)
            bfr[ni] = *(const bf16x8*)(&Bs[(wn + ni * 16 + lr) * 40 + lg * 8]);
#pragma unroll
        for (int mi = 0; mi < 4; mi++)
#pragma unroll
            for (int ni = 0; ni < 2; ni++)
                acc[mi][ni] = __builtin_amdgcn_mfma_f32_16x16x32_bf16(
                    af[mi], bfr[ni], acc[mi][ni], 0, 0, 0);
    }

    // C/D layout: col = lane&15, row = (lane>>4)*4 + reg.
#pragma unroll
    for (int mi = 0; mi < 4; mi++) {
#pragma unroll
        for (int ni = 0; ni < 2; ni++) {
            const int gcol = n0 + wn + ni * 16 + lr;
            const float bv = bias[gcol];
            const int grow0 = m0 + wm + mi * 16 + lg * 4;
            if (mode == 2) {
                int b = grow0 >> 11, s = grow0 & (S_LEN - 1);
                int h = gcol >> 6, dh = gcol & 63;
                unsigned short us[4];
#pragma unroll
                for (int r = 0; r < 4; r++) us[r] = f2bf(acc[mi][ni][r] + bv);
                size_t di = ((size_t)(b * NH + h) * DH + dh) * S_LEN + s;
                *(ushort2*)(&dstb[di])     = ushort2{us[0], us[1]};
                *(ushort2*)(&dstb[di + 2]) = ushort2{us[2], us[3]};
            } else {
#pragma unroll
                for (int r = 0; r < 4; r++) {
                    int grow = grow0 + r;
                    float v = acc[mi][ni][r] + bv;
                    if (mode == 3) {
                        dstf[(size_t)grow * DM + gcol] = v;
                    } else {
                        int b = grow >> 11, s = grow & (S_LEN - 1);
                        int h = gcol >> 6, dh = gcol & 63;
                        dstb[((size_t)(b * NH + h) * S_LEN + s) * DH + dh] = f2bf(v);
                    }
                }
            }
        }
    }
}

// Flash attention: grid (S/64, B*H), 4 waves, 16 q-rows/wave, kv-step 128.
__global__ __launch_bounds__(256)
void attn(const unsigned short* __restrict__ q_ws,
          const unsigned short* __restrict__ k_ws,
          const unsigned short* __restrict__ vt_ws,
          const unsigned* __restrict__ mbits,
          unsigned short* __restrict__ ctx_ws)
{
    __shared__ __align__(16) unsigned short P_lds[4][16 * 136];  // 16 x 128 (+8 pad)
    const int tid = threadIdx.x, lane = tid & 63, w = tid >> 6;
    const int lr = lane & 15, lg = lane >> 4;
    const int bh = blockIdx.y;
    const int b  = bh >> 4;
    const int h  = bh & 15;
    const int q0 = blockIdx.x * 64 + w * 16;

    const unsigned short* qh = q_ws + (size_t)bh * S_LEN * DH;
    const unsigned short* kh = k_ws + (size_t)bh * S_LEN * DH;
    const unsigned short* vh = vt_ws + (size_t)bh * DH * S_LEN;
    const unsigned* mrow = mbits + (size_t)(b * S_LEN) * (S_LEN / 32);

    bf16x8 aq[2];
#pragma unroll
    for (int c = 0; c < 2; c++)
        aq[c] = *(const bf16x8*)(&qh[(size_t)(q0 + lr) * DH + c * 32 + lg * 8]);

    f32x4 acc[4];
#pragma unroll
    for (int di = 0; di < 4; di++) acc[di] = f32x4{0.f, 0.f, 0.f, 0.f};
    float mrun[4], lrun[4];
#pragma unroll
    for (int r = 0; r < 4; r++) { mrun[r] = -1e30f; lrun[r] = 0.f; }

    for (int kv0 = 0; kv0 < S_LEN; kv0 += 128) {
        // packed mask: per r, 4 words = 128 kv bits (broadcast load, 16B)
        unsigned mw[4][4];
#pragma unroll
        for (int r = 0; r < 4; r++) {
            uint4 t = *(const uint4*)(&mrow[(size_t)(q0 + lg * 4 + r) * (S_LEN / 32) + (kv0 >> 5)]);
            mw[r][0] = t.x; mw[r][1] = t.y; mw[r][2] = t.z; mw[r][3] = t.w;
        }
        f32x4 sf[8];
#pragma unroll
        for (int ni = 0; ni < 8; ni++) {
            const unsigned short* kr = &kh[(size_t)(kv0 + ni * 16 + lr) * DH + lg * 8];
            bf16x8 bk0 = *(const bf16x8*)(kr);
            bf16x8 bk1 = *(const bf16x8*)(kr + 32);
            f32x4 t = __builtin_amdgcn_mfma_f32_16x16x32_bf16(aq[0], bk0, f32x4{0.f,0.f,0.f,0.f}, 0,0,0);
            t = __builtin_amdgcn_mfma_f32_16x16x32_bf16(aq[1], bk1, t, 0,0,0);
            sf[ni] = t;
        }
#pragma unroll
        for (int ni = 0; ni < 8; ni++)
#pragma unroll
            for (int r = 0; r < 4; r++) {
                unsigned bit = (mw[r][ni >> 1] >> ((ni & 1) * 16 + lr)) & 1u;
                sf[ni][r] = sf[ni][r] * 0.125f + (bit ? -9e10f : 0.0f);
            }
        float mnew[4], alpha[4];
#pragma unroll
        for (int r = 0; r < 4; r++) {
            float v = sf[0][r];
#pragma unroll
            for (int ni = 1; ni < 8; ni++) v = fmaxf(v, sf[ni][r]);
            v = fmaxf(v, __shfl_xor(v, 1));
            v = fmaxf(v, __shfl_xor(v, 2));
            v = fmaxf(v, __shfl_xor(v, 4));
            v = fmaxf(v, __shfl_xor(v, 8));
            mnew[r] = fmaxf(mrun[r], v);
            alpha[r] = __expf(fminf(mrun[r] - mnew[r], 0.f));
            mrun[r] = mnew[r];
        }
        float rs[4] = {0.f, 0.f, 0.f, 0.f};
#pragma unroll
        for (int ni = 0; ni < 8; ni++)
#pragma unroll
            for (int r = 0; r < 4; r++) {
                float p = __expf(fminf(sf[ni][r] - mnew[r], 0.f));
                sf[ni][r] = p;
                rs[r] += p;
            }
#pragma unroll
        for (int r = 0; r < 4; r++) {
            float v = rs[r];
            v += __shfl_xor(v, 1);
            v += __shfl_xor(v, 2);
            v += __shfl_xor(v, 4);
            v += __shfl_xor(v, 8);
            lrun[r] = alpha[r] * lrun[r] + v;
        }
#pragma unroll
        for (int di = 0; di < 4; di++)
#pragma unroll
            for (int r = 0; r < 4; r++) acc[di][r] *= alpha[r];

        // P (C-layout) -> LDS -> A-layout fragments. Per-wave region.
        unsigned short* pl = &P_lds[w][0];
#pragma unroll
        for (int ni = 0; ni < 8; ni++)
#pragma unroll
            for (int r = 0; r < 4; r++)
                pl[(lg * 4 + r) * 136 + ni * 16 + lr] = f2bf(sf[ni][r]);

        bf16x8 ap[4];
#pragma unroll
        for (int c = 0; c < 4; c++)
            ap[c] = *(const bf16x8*)(&pl[lr * 136 + c * 32 + lg * 8]);
#pragma unroll
        for (int di = 0; di < 4; di++) {
            const unsigned short* vr = &vh[(size_t)(di * 16 + lr) * S_LEN + kv0 + lg * 8];
#pragma unroll
            for (int c = 0; c < 4; c++) {
                bf16x8 bv = *(const bf16x8*)(vr + c * 32);
                acc[di] = __builtin_amdgcn_mfma_f32_16x16x32_bf16(ap[c], bv, acc[di], 0, 0, 0);
            }
        }
    }

#pragma unroll
    for (int di = 0; di < 4; di++)
#pragma unroll
        for (int r = 0; r < 4; r++) {
            int qrow = q0 + lg * 4 + r;
            int col = h * DH + di * 16 + lr;
            float inv = 1.0f / fmaxf(lrun[r], 1e-37f);
            ctx_ws[((size_t)(b * S_LEN + qrow)) * DM + col] = f2bf(acc[di][r] * inv);
        }
}

extern "C" void kernel_launch(void* const* d_in, const int* in_sizes, int n_in,
                              void* d_out, int out_size, void* d_ws, size_t ws_size,
                              hipStream_t stream)
{
    (void)in_sizes; (void)n_in; (void)out_size; (void)ws_size;
    const float* Q  = (const float*)d_in[0];
    const float* K  = (const float*)d_in[1];
    const float* V  = (const float*)d_in[2];
    const int*   Mk = (const int*)d_in[3];
    const float* Wq = (const float*)d_in[4];
    const float* bq = (const float*)d_in[5];
    const float* Wk = (const float*)d_in[6];
    const float* bk = (const float*)d_in[7];
    const float* Wv = (const float*)d_in[8];
    const float* bv = (const float*)d_in[9];
    const float* Wo = (const float*)d_in[10];
    const float* bo = (const float*)d_in[11];

    const int NX = MROWS * DM;   // 4194304
    const int NW = DM * DM;      // 1048576

    unsigned short* Xb    = (unsigned short*)d_ws;            // 8 MB (also ctx after attn)
    unsigned short* Wb    = Xb + (size_t)NX;                  // 2 MB
    unsigned short* q_ws  = Wb + (size_t)NW;                  // 8 MB
    unsigned short* k_ws  = q_ws + (size_t)NX;                // 8 MB
    unsigned short* vt_ws = k_ws + (size_t)NX;                // 8 MB
    unsigned*       mbits = (unsigned*)(vt_ws + (size_t)NX);  // 1 MB
    float* out = (float*)d_out;

    dim3 blk(256);
    pack_mask<<<dim3(1024), blk, 0, stream>>>(Mk, mbits);

    cvt2<<<dim3(2048, 2), blk, 0, stream>>>(Q, Xb, NX, Wq, Wb, NW);
    gemm_bt<<<dim3(16, 32), blk, 0, stream>>>(Xb, Wb, bq, q_ws, nullptr, 0);

    cvt2<<<dim3(2048, 2), blk, 0, stream>>>(K, Xb, NX, Wk, Wb, NW);
    gemm_bt<<<dim3(16, 32), blk, 0, stream>>>(Xb, Wb, bk, k_ws, nullptr, 1);

    cvt2<<<dim3(2048, 2), blk, 0, stream>>>(V, Xb, NX, Wv, Wb, NW);
    gemm_bt<<<dim3(16, 32), blk, 0, stream>>>(Xb, Wb, bv, vt_ws, nullptr, 2);

    attn<<<dim3(32, 32), blk, 0, stream>>>(q_ws, k_ws, vt_ws, mbits, Xb);

    cvt2<<<dim3(512, 1), blk, 0, stream>>>(Wo, Wb, NW, nullptr, nullptr, 0);
    gemm_bt<<<dim3(16, 32), blk, 0, stream>>>(Xb, Wb, bo, nullptr, out, 3);
}

// Round 5
// 504.038 us; speedup vs baseline: 1.3056x; 1.0076x over previous
//
#include <hip/hip_runtime.h>
#include <hip/hip_bf16.h>

// B=2, S=2048, D_MODEL=1024, H=16, D_HEAD=64.
// I/O fp32 (verified R3); mask int32 (nonzero = masked). Internals bf16 MFMA.
// R4: attn is latency-bound at 16 waves/CU cap -> kv-split (z=2) + merge.

typedef __bf16 bf16x8 __attribute__((ext_vector_type(8)));
typedef float f32x4 __attribute__((ext_vector_type(4)));

#define S_LEN 2048
#define DM 1024
#define NH 16
#define DH 64
#define MROWS 4096  // B*S
#define NSPLIT 2
#define RTOT (32 * S_LEN)  // bh-major rows = 65536

static __device__ __forceinline__ unsigned short f2bf(float f) {
    __hip_bfloat16 h = __float2bfloat16(f);
    unsigned short u; __builtin_memcpy(&u, &h, 2); return u;
}

static __device__ __forceinline__ bf16x8 cvt8(float4 a, float4 b) {
    bf16x8 o;
    o[0] = (__bf16)a.x; o[1] = (__bf16)a.y; o[2] = (__bf16)a.z; o[3] = (__bf16)a.w;
    o[4] = (__bf16)b.x; o[5] = (__bf16)b.y; o[6] = (__bf16)b.z; o[7] = (__bf16)b.w;
    return o;
}

// fp32 -> bf16, two tensors per launch (blockIdx.y selects).
__global__ __launch_bounds__(256)
void cvt2(const float* __restrict__ sA, unsigned short* __restrict__ dA, int nA,
          const float* __restrict__ sB, unsigned short* __restrict__ dB, int nB)
{
    const float* s = blockIdx.y ? sB : sA;
    unsigned short* d = blockIdx.y ? dB : dA;
    int n = blockIdx.y ? nB : nA;
    int i = (blockIdx.x * 256 + threadIdx.x) * 8;
    if (i < n) {
        float4 a = *(const float4*)(s + i);
        float4 b = *(const float4*)(s + i + 4);
        *(bf16x8*)(d + i) = cvt8(a, b);
    }
}

// mask int32 [B*S][S] -> bit-packed [B*S][S/32] uint32 (bit kv&31 of word kv>>5)
__global__ __launch_bounds__(256)
void pack_mask(const int* __restrict__ m, unsigned* __restrict__ mb)
{
    const int lane = threadIdx.x & 63, w = threadIdx.x >> 6;
    const int row = blockIdx.x * 4 + w;
    const int* src = m + (size_t)row * S_LEN;
    unsigned* dst = mb + (size_t)row * (S_LEN / 32);
    for (int i = 0; i < 32; i++) {
        int v = src[i * 64 + lane];
        unsigned long long bm = __ballot(v != 0);
        if (lane == 0) { dst[i * 2] = (unsigned)bm; dst[i * 2 + 1] = (unsigned)(bm >> 32); }
    }
}

// Y = X @ W^T + bias. X bf16 (4096x1024), W bf16 (1024x1024). Tile 128Mx64N.
__global__ __launch_bounds__(256)
void gemm_bt(const unsigned short* __restrict__ X, const unsigned short* __restrict__ W,
             const float* __restrict__ bias,
             unsigned short* __restrict__ dstb, float* __restrict__ dstf, int mode)
{
    __shared__ __align__(16) unsigned short As[128 * 40];
    __shared__ __align__(16) unsigned short Bs[64 * 40];
    const int tid  = threadIdx.x;
    const int m0   = blockIdx.y * 128;
    const int n0   = blockIdx.x * 64;
    const int lane = tid & 63;
    const int w    = tid >> 6;
    const int wm   = (w >> 1) * 64, wn = (w & 1) * 32;
    const int lr   = lane & 15;
    const int lg   = lane >> 4;

    f32x4 acc[4][2];
#pragma unroll
    for (int i = 0; i < 4; i++)
#pragma unroll
        for (int j = 0; j < 2; j++) acc[i][j] = f32x4{0.f, 0.f, 0.f, 0.f};

    for (int k0 = 0; k0 < DM; k0 += 32) {
        __syncthreads();
        {
            int r = tid >> 2, c = (tid & 3) * 8;
            *(bf16x8*)(&As[r * 40 + c]) = *(const bf16x8*)(&X[(size_t)(m0 + r) * DM + k0 + c]);
            int r1 = (tid + 256) >> 2, c1 = ((tid + 256) & 3) * 8;
            *(bf16x8*)(&As[r1 * 40 + c1]) = *(const bf16x8*)(&X[(size_t)(m0 + r1) * DM + k0 + c1]);
            *(bf16x8*)(&Bs[r * 40 + c]) = *(const bf16x8*)(&W[(size_t)(n0 + r) * DM + k0 + c]);
        }
        __syncthreads();
        bf16x8 af[4], bfr[2];
#pragma unroll
        for (int mi = 0; mi < 4; mi++)
            af[mi] = *(const bf16x8*)(&As[(wm + mi * 16 + lr) * 40 + lg * 8]);
#pragma unroll
        for (int ni = 0; ni < 2; ni++)
            bfr[ni] = *(const bf16x8*)(&Bs[(wn + ni * 16 + lr) * 40 + lg * 8]);
#pragma unroll
        for (int mi = 0; mi < 4; mi++)
#pragma unroll
            for (int ni = 0; ni < 2; ni++)
                acc[mi][ni] = __builtin_amdgcn_mfma_f32_16x16x32_bf16(
                    af[mi], bfr[ni], acc[mi][ni], 0, 0, 0);
    }

    // C/D layout: col = lane&15, row = (lane>>4)*4 + reg.
#pragma unroll
    for (int mi = 0; mi < 4; mi++) {
#pragma unroll
        for (int ni = 0; ni < 2; ni++) {
            const int gcol = n0 + wn + ni * 16 + lr;
            const float bv = bias[gcol];
            const int grow0 = m0 + wm + mi * 16 + lg * 4;
            if (mode == 2) {
                int b = grow0 >> 11, s = grow0 & (S_LEN - 1);
                int h = gcol >> 6, dh = gcol & 63;
                unsigned short us[4];
#pragma unroll
                for (int r = 0; r < 4; r++) us[r] = f2bf(acc[mi][ni][r] + bv);
                size_t di = ((size_t)(b * NH + h) * DH + dh) * S_LEN + s;
                *(ushort2*)(&dstb[di])     = ushort2{us[0], us[1]};
                *(ushort2*)(&dstb[di + 2]) = ushort2{us[2], us[3]};
            } else {
#pragma unroll
                for (int r = 0; r < 4; r++) {
                    int grow = grow0 + r;
                    float v = acc[mi][ni][r] + bv;
                    if (mode == 3) {
                        dstf[(size_t)grow * DM + gcol] = v;
                    } else {
                        int b = grow >> 11, s = grow & (S_LEN - 1);
                        int h = gcol >> 6, dh = gcol & 63;
                        dstb[((size_t)(b * NH + h) * S_LEN + s) * DH + dh] = f2bf(v);
                    }
                }
            }
        }
    }
}

// Flash attention, kv-split. grid (S/64, B*H, NSPLIT), 4 waves, 16 q-rows/wave,
// kv-step 128, 8 iters per split. Writes unnormalized fp32 partial O + (m,l).
__global__ __launch_bounds__(256)
void attn(const unsigned short* __restrict__ q_ws,
          const unsigned short* __restrict__ k_ws,
          const unsigned short* __restrict__ vt_ws,
          const unsigned* __restrict__ mbits,
          float* __restrict__ pO, float* __restrict__ pm, float* __restrict__ pl)
{
    __shared__ __align__(16) unsigned short P_lds[4][16 * 136];
    const int tid = threadIdx.x, lane = tid & 63, w = tid >> 6;
    const int lr = lane & 15, lg = lane >> 4;
    const int bh = blockIdx.y;
    const int b  = bh >> 4;
    const int sp = blockIdx.z;
    const int q0 = blockIdx.x * 64 + w * 16;
    const int kvbase = sp * (S_LEN / NSPLIT);

    const unsigned short* qh = q_ws + (size_t)bh * S_LEN * DH;
    const unsigned short* kh = k_ws + (size_t)bh * S_LEN * DH;
    const unsigned short* vh = vt_ws + (size_t)bh * DH * S_LEN;
    const unsigned* mrow = mbits + (size_t)(b * S_LEN) * (S_LEN / 32);

    bf16x8 aq[2];
#pragma unroll
    for (int c = 0; c < 2; c++)
        aq[c] = *(const bf16x8*)(&qh[(size_t)(q0 + lr) * DH + c * 32 + lg * 8]);

    f32x4 acc[4];
#pragma unroll
    for (int di = 0; di < 4; di++) acc[di] = f32x4{0.f, 0.f, 0.f, 0.f};
    float mrun[4], lrun[4];
#pragma unroll
    for (int r = 0; r < 4; r++) { mrun[r] = -1e30f; lrun[r] = 0.f; }

    for (int it = 0; it < S_LEN / NSPLIT; it += 128) {
        const int kv0 = kvbase + it;
        unsigned mw[4][4];
#pragma unroll
        for (int r = 0; r < 4; r++) {
            uint4 t = *(const uint4*)(&mrow[(size_t)(q0 + lg * 4 + r) * (S_LEN / 32) + (kv0 >> 5)]);
            mw[r][0] = t.x; mw[r][1] = t.y; mw[r][2] = t.z; mw[r][3] = t.w;
        }
        f32x4 sf[8];
#pragma unroll
        for (int ni = 0; ni < 8; ni++) {
            const unsigned short* kr = &kh[(size_t)(kv0 + ni * 16 + lr) * DH + lg * 8];
            bf16x8 bk0 = *(const bf16x8*)(kr);
            bf16x8 bk1 = *(const bf16x8*)(kr + 32);
            f32x4 t = __builtin_amdgcn_mfma_f32_16x16x32_bf16(aq[0], bk0, f32x4{0.f,0.f,0.f,0.f}, 0,0,0);
            t = __builtin_amdgcn_mfma_f32_16x16x32_bf16(aq[1], bk1, t, 0,0,0);
            sf[ni] = t;
        }
#pragma unroll
        for (int ni = 0; ni < 8; ni++)
#pragma unroll
            for (int r = 0; r < 4; r++) {
                unsigned bit = (mw[r][ni >> 1] >> ((ni & 1) * 16 + lr)) & 1u;
                sf[ni][r] = sf[ni][r] * 0.125f + (bit ? -9e10f : 0.0f);
            }
        float mnew[4], alpha[4];
#pragma unroll
        for (int r = 0; r < 4; r++) {
            float v = sf[0][r];
#pragma unroll
            for (int ni = 1; ni < 8; ni++) v = fmaxf(v, sf[ni][r]);
            v = fmaxf(v, __shfl_xor(v, 1));
            v = fmaxf(v, __shfl_xor(v, 2));
            v = fmaxf(v, __shfl_xor(v, 4));
            v = fmaxf(v, __shfl_xor(v, 8));
            mnew[r] = fmaxf(mrun[r], v);
            alpha[r] = __expf(fminf(mrun[r] - mnew[r], 0.f));
            mrun[r] = mnew[r];
        }
        float rs[4] = {0.f, 0.f, 0.f, 0.f};
#pragma unroll
        for (int ni = 0; ni < 8; ni++)
#pragma unroll
            for (int r = 0; r < 4; r++) {
                float p = __expf(fminf(sf[ni][r] - mnew[r], 0.f));
                sf[ni][r] = p;
                rs[r] += p;
            }
#pragma unroll
        for (int r = 0; r < 4; r++) {
            float v = rs[r];
            v += __shfl_xor(v, 1);
            v += __shfl_xor(v, 2);
            v += __shfl_xor(v, 4);
            v += __shfl_xor(v, 8);
            lrun[r] = alpha[r] * lrun[r] + v;
        }
#pragma unroll
        for (int di = 0; di < 4; di++)
#pragma unroll
            for (int r = 0; r < 4; r++) acc[di][r] *= alpha[r];

        // P (C-layout) -> LDS -> A-layout fragments. Per-wave region.
        unsigned short* pl_ = &P_lds[w][0];
#pragma unroll
        for (int ni = 0; ni < 8; ni++)
#pragma unroll
            for (int r = 0; r < 4; r++)
                pl_[(lg * 4 + r) * 136 + ni * 16 + lr] = f2bf(sf[ni][r]);

        bf16x8 ap[4];
#pragma unroll
        for (int c = 0; c < 4; c++)
            ap[c] = *(const bf16x8*)(&pl_[lr * 136 + c * 32 + lg * 8]);
#pragma unroll
        for (int di = 0; di < 4; di++) {
            const unsigned short* vr = &vh[(size_t)(di * 16 + lr) * S_LEN + kv0 + lg * 8];
#pragma unroll
            for (int c = 0; c < 4; c++) {
                bf16x8 bv = *(const bf16x8*)(vr + c * 32);
                acc[di] = __builtin_amdgcn_mfma_f32_16x16x32_bf16(ap[c], bv, acc[di], 0, 0, 0);
            }
        }
    }

    // Partials: rows bh*2048+q (bh-major), unnormalized O + per-row m,l.
    float* po = pO + ((size_t)sp * RTOT + (size_t)bh * S_LEN) * DH;
#pragma unroll
    for (int di = 0; di < 4; di++)
#pragma unroll
        for (int r = 0; r < 4; r++)
            po[(size_t)(q0 + lg * 4 + r) * DH + di * 16 + lr] = acc[di][r];
    if (lr == 0) {
#pragma unroll
        for (int r = 0; r < 4; r++) {
            size_t ridx = (size_t)sp * RTOT + (size_t)bh * S_LEN + q0 + lg * 4 + r;
            pm[ridx] = mrun[r];
            pl[ridx] = lrun[r];
        }
    }
}

// Merge the NSPLIT partials -> ctx bf16 [b*S+q][h*64+dh]. lane = dh.
__global__ __launch_bounds__(256)
void merge(const float* __restrict__ pO, const float* __restrict__ pm,
           const float* __restrict__ pl, unsigned short* __restrict__ ctx)
{
    const int lane = threadIdx.x & 63, w = threadIdx.x >> 6;
#pragma unroll
    for (int i = 0; i < 8; i++) {
        int ridx = (blockIdx.x * 4 + w) * 8 + i;
        int bh = ridx >> 11, q = ridx & (S_LEN - 1);
        int b = bh >> 4, h = bh & 15;
        float m1 = pm[ridx], m2 = pm[RTOT + ridx];
        float l1 = pl[ridx], l2 = pl[RTOT + ridx];
        float m = fmaxf(m1, m2);
        float c1 = __expf(fminf(m1 - m, 0.f));
        float c2 = __expf(fminf(m2 - m, 0.f));
        float inv = 1.0f / fmaxf(c1 * l1 + c2 * l2, 1e-37f);
        float o1 = pO[(size_t)ridx * DH + lane];
        float o2 = pO[((size_t)RTOT + ridx) * DH + lane];
        float o = (c1 * o1 + c2 * o2) * inv;
        ctx[((size_t)(b * S_LEN + q)) * DM + h * DH + lane] = f2bf(o);
    }
}

extern "C" void kernel_launch(void* const* d_in, const int* in_sizes, int n_in,
                              void* d_out, int out_size, void* d_ws, size_t ws_size,
                              hipStream_t stream)
{
    (void)in_sizes; (void)n_in; (void)out_size; (void)ws_size;
    const float* Q  = (const float*)d_in[0];
    const float* K  = (const float*)d_in[1];
    const float* V  = (const float*)d_in[2];
    const int*   Mk = (const int*)d_in[3];
    const float* Wq = (const float*)d_in[4];
    const float* bq = (const float*)d_in[5];
    const float* Wk = (const float*)d_in[6];
    const float* bk = (const float*)d_in[7];
    const float* Wv = (const float*)d_in[8];
    const float* bv = (const float*)d_in[9];
    const float* Wo = (const float*)d_in[10];
    const float* bo = (const float*)d_in[11];

    const int NX = MROWS * DM;   // 4194304
    const int NW = DM * DM;      // 1048576

    unsigned short* Xb    = (unsigned short*)d_ws;            // 8 MB (ctx after merge)
    unsigned short* Wb    = Xb + (size_t)NX;                  // 2 MB
    unsigned short* q_ws  = Wb + (size_t)NW;                  // 8 MB
    unsigned short* k_ws  = q_ws + (size_t)NX;                // 8 MB
    unsigned short* vt_ws = k_ws + (size_t)NX;                // 8 MB
    unsigned*       mbits = (unsigned*)(vt_ws + (size_t)NX);  // 1 MB
    float*          pO    = (float*)(mbits + (size_t)MROWS * (S_LEN / 32)); // 32 MB
    float*          pm    = pO + (size_t)NSPLIT * RTOT * DH;  // 0.5 MB
    float*          plv   = pm + (size_t)NSPLIT * RTOT;       // 0.5 MB
    float* out = (float*)d_out;

    dim3 blk(256);
    pack_mask<<<dim3(1024), blk, 0, stream>>>(Mk, mbits);

    cvt2<<<dim3(2048, 2), blk, 0, stream>>>(Q, Xb, NX, Wq, Wb, NW);
    gemm_bt<<<dim3(16, 32), blk, 0, stream>>>(Xb, Wb, bq, q_ws, nullptr, 0);

    cvt2<<<dim3(2048, 2), blk, 0, stream>>>(K, Xb, NX, Wk, Wb, NW);
    gemm_bt<<<dim3(16, 32), blk, 0, stream>>>(Xb, Wb, bk, k_ws, nullptr, 1);

    cvt2<<<dim3(2048, 2), blk, 0, stream>>>(V, Xb, NX, Wv, Wb, NW);
    gemm_bt<<<dim3(16, 32), blk, 0, stream>>>(Xb, Wb, bv, vt_ws, nullptr, 2);

    attn<<<dim3(32, 32, NSPLIT), blk, 0, stream>>>(q_ws, k_ws, vt_ws, mbits, pO, pm, plv);
    merge<<<dim3(2048), blk, 0, stream>>>(pO, pm, plv, Xb);

    cvt2<<<dim3(512, 1), blk, 0, stream>>>(Wo, Wb, NW, nullptr, nullptr, 0);
    gemm_bt<<<dim3(16, 32), blk, 0, stream>>>(Xb, Wb, bo, nullptr, out, 3);
}